// Round 1
// baseline (294.394 us; speedup 1.0000x reference)
//
#include <hip/hip_runtime.h>
#include <math.h>

#define NB 16
#define NC 3
#define NH 512
#define NW 512
#define NHW (NH*NW)
#define KSEL 26214u
#define PI_F 3.14159265358979f

// ---- ws layout (float units) ----
#define DARK_OFF   0
#define TMP_OFF    (NB*NHW)                  // 4,194,304
#define HIST_OFF   (TMP_OFF + NB*NC*NHW)     // 16,777,216
#define STATE_OFF  (HIST_OFF + NB*256)
#define ABITS_OFF  (STATE_OFF + NB*4)
#define PBUF_OFF   (ABITS_OFF + NB*3)
#define GW_OFF     (PBUF_OFF + NB*32)
#define RF_OFF     (GW_OFF + 32)
// total ~16.81M floats ~= 67.3 MB of ws

// pointwise chain through tone (pre tone-scale): defog -> wb -> gamma -> tone
__device__ __forceinline__ float chain_tt(float xv, float dv, float omega, float Aval,
                                          float wbp, float g, const float* tone) {
  float t = fminf(fmaxf(1.f - omega*dv, 0.1f), 1.f);
  float J = (xv - Aval)/t + Aval;
  J = fminf(fmaxf(J, 0.f), 1.f);
  float v = J * wbp;
  float u = __powf(fmaxf(v, 1e-4f), g);
  float tt = 0.f;
#pragma unroll
  for (int i = 0; i < 8; i++)
    tt = fmaf(fminf(fmaxf(u - 0.125f*(float)i, 0.f), 0.125f), tone[i], tt);
  return tt;
}

// K1: parse params, build gaussian weights, zero hist + A
__global__ void k_params(const float* __restrict__ p, float* __restrict__ pbuf,
                         float* __restrict__ gw, unsigned* __restrict__ hist,
                         unsigned* __restrict__ abits) {
  int tid = threadIdx.x;
  if (tid < NB) {
    const float* pp = p + tid*15;
    float* ob = pbuf + tid*32;
    float omega = (tanhf(pp[0])+1.f)*0.5f*0.9f + 0.1f;
    float wb0 = 1.0f;  // mask=0 -> tanh01(0)*1-0.5=0 -> exp(0)=1
    float wb1 = expf((tanhf(pp[2])+1.f)*0.5f - 0.5f);
    float wb2 = expf((tanhf(pp[3])+1.f)*0.5f - 0.5f);
    float denom = 0.27f*wb0 + 0.67f*wb1 + 0.06f*wb2 + 1e-5f;
    float lg = logf(3.0f);
    float g = expf((tanhf(pp[4])+1.f)*0.5f*(2.f*lg) - lg);
    float ts = 0.f, tone[8];
    for (int i = 0; i < 8; i++) { tone[i] = (tanhf(pp[5+i])+1.f)*0.5f*1.5f + 0.5f; ts += tone[i]; }
    ts += 1e-30f;
    ob[0] = omega; ob[1] = wb0/denom; ob[2] = wb1/denom; ob[3] = wb2/denom; ob[4] = g;
    for (int i = 0; i < 8; i++) ob[5+i] = tone[i];
    ob[13] = 8.0f/ts;            // tonescale
    ob[14] = tanhf(pp[13]);      // contrast c
    ob[15] = (tanhf(pp[14])+1.f)*0.5f*5.0f;  // sharpen
  }
  if (tid == 32) {
    float wv[25], wsum = 0.f;
    for (int i = 0; i < 25; i++) { float d = (float)(i-12)/5.0f; wv[i] = expf(-0.5f*d*d); wsum += wv[i]; }
    for (int i = 0; i < 25; i++) gw[i] = wv[i]/wsum;
  }
  for (int i = tid; i < NB*256; i += blockDim.x) hist[i] = 0u;
  if (tid < NB*3) abits[tid] = 0u;
}

// K2: dark channel + level-0 radix histogram (top byte). grid (128, NB) x 256
__global__ void k_dark(const float* __restrict__ x, float* __restrict__ dark,
                       unsigned* __restrict__ hist) {
  __shared__ unsigned lh[8*256];
  int tid = threadIdx.x, b = blockIdx.y;
  for (int i = tid; i < 8*256; i += 256) lh[i] = 0u;
  __syncthreads();
  const float4* x0 = (const float4*)(x + (size_t)b*NC*NHW);
  const float4* x1 = x0 + NHW/4;
  const float4* x2 = x1 + NHW/4;
  float4* d4 = (float4*)(dark + (size_t)b*NHW);
  unsigned* lhm = lh + (tid & 7)*256;
  int base = blockIdx.x*512 + tid;
#pragma unroll
  for (int it = 0; it < 2; it++) {
    int i = base + it*256;
    float4 a = x0[i], g = x1[i], r = x2[i];
    float4 d;
    d.x = fminf(fminf(a.x,g.x),r.x); d.y = fminf(fminf(a.y,g.y),r.y);
    d.z = fminf(fminf(a.z,g.z),r.z); d.w = fminf(fminf(a.w,g.w),r.w);
    d4[i] = d;
    atomicAdd(&lhm[__float_as_uint(d.x)>>24], 1u);
    atomicAdd(&lhm[__float_as_uint(d.y)>>24], 1u);
    atomicAdd(&lhm[__float_as_uint(d.z)>>24], 1u);
    atomicAdd(&lhm[__float_as_uint(d.w)>>24], 1u);
  }
  __syncthreads();
  unsigned s = 0;
  for (int r = 0; r < 8; r++) s += lh[r*256 + tid];
  if (s) atomicAdd(&hist[b*256 + tid], s);
}

// scan one radix level: find bin containing k-th largest, update state, zero hist
__global__ void k_scan(unsigned* __restrict__ hist, unsigned* __restrict__ state, int level) {
  int b = blockIdx.x, lane = threadIdx.x;  // 64 threads = 1 wave
  unsigned cnt[4], s = 0;
#pragma unroll
  for (int j = 0; j < 4; j++) { cnt[j] = hist[b*256 + (255 - (lane*4+j))]; s += cnt[j]; }
  unsigned inc = s;
  for (int off = 1; off < 64; off <<= 1) {
    unsigned n = __shfl_up(inc, off);
    if (lane >= off) inc += n;
  }
  unsigned excl = inc - s;
  unsigned k = (level == 0) ? KSEL : state[b*4+1];
  if (excl < k && k <= inc) {
    unsigned run = excl, rem = 0; int binj = -1;
#pragma unroll
    for (int j = 0; j < 4; j++) {
      unsigned nb = run + cnt[j];
      if (binj < 0 && k <= nb) { binj = j; rem = k - run; }
      run = nb;
    }
    unsigned bin = 255u - (unsigned)(lane*4 + binj);
    int shift = 24 - 8*level;
    unsigned prefix = ((level == 0) ? 0u : state[b*4+0]) | (bin << shift);
    state[b*4+0] = prefix; state[b*4+1] = rem;
    if (level == 3) state[b*4+2] = prefix;   // exact tau bits
  }
#pragma unroll
  for (int i = 0; i < 4; i++) hist[b*256 + lane*4 + i] = 0u;
}

// radix refine levels 1..3 over dark bits. grid (64, NB) x 256
__global__ void k_hist(const unsigned* __restrict__ darkbits, unsigned* __restrict__ hist,
                       const unsigned* __restrict__ state, int level) {
  __shared__ unsigned lh[256];
  int tid = threadIdx.x, b = blockIdx.y;
  lh[tid] = 0u;
  __syncthreads();
  int shift = 24 - 8*level;
  unsigned mask = ~((1u << (shift+8)) - 1u);
  unsigned prefix = state[b*4];
  const uint4* dp = (const uint4*)(darkbits + (size_t)b*NHW);
  int base = blockIdx.x*1024 + tid;
#pragma unroll
  for (int it = 0; it < 4; it++) {
    uint4 u = dp[base + it*256];
    if ((u.x & mask) == prefix) atomicAdd(&lh[(u.x>>shift)&0xFF], 1u);
    if ((u.y & mask) == prefix) atomicAdd(&lh[(u.y>>shift)&0xFF], 1u);
    if ((u.z & mask) == prefix) atomicAdd(&lh[(u.z>>shift)&0xFF], 1u);
    if ((u.w & mask) == prefix) atomicAdd(&lh[(u.w>>shift)&0xFF], 1u);
  }
  __syncthreads();
  if (lh[tid]) atomicAdd(&hist[b*256 + tid], lh[tid]);
}

// A[b,c] = max x[b,c,p] over pixels with dark >= tau. grid (128, NB) x 256
__global__ void k_amax(const float* __restrict__ x, const float* __restrict__ dark,
                       const unsigned* __restrict__ state, unsigned* __restrict__ abits) {
  __shared__ unsigned sm[3];
  int tid = threadIdx.x, b = blockIdx.y;
  if (tid < 3) sm[tid] = 0u;
  __syncthreads();
  float tau = __uint_as_float(state[b*4+2]);
  const float4* x0 = (const float4*)(x + (size_t)b*NC*NHW);
  const float4* x1 = x0 + NHW/4;
  const float4* x2 = x1 + NHW/4;
  const float4* dp = (const float4*)(dark + (size_t)b*NHW);
  float m0 = 0.f, m1 = 0.f, m2 = 0.f;
  int base = blockIdx.x*512 + tid;
#pragma unroll
  for (int it = 0; it < 2; it++) {
    int i = base + it*256;
    float4 d = dp[i];
    bool s0 = d.x >= tau, s1 = d.y >= tau, s2 = d.z >= tau, s3 = d.w >= tau;
    if (s0 | s1 | s2 | s3) {
      float4 a = x0[i], g = x1[i], r = x2[i];
      if (s0) { m0 = fmaxf(m0,a.x); m1 = fmaxf(m1,g.x); m2 = fmaxf(m2,r.x); }
      if (s1) { m0 = fmaxf(m0,a.y); m1 = fmaxf(m1,g.y); m2 = fmaxf(m2,r.y); }
      if (s2) { m0 = fmaxf(m0,a.z); m1 = fmaxf(m1,g.z); m2 = fmaxf(m2,r.z); }
      if (s3) { m0 = fmaxf(m0,a.w); m1 = fmaxf(m1,g.w); m2 = fmaxf(m2,r.w); }
    }
  }
  atomicMax(&sm[0], __float_as_uint(m0));
  atomicMax(&sm[1], __float_as_uint(m1));
  atomicMax(&sm[2], __float_as_uint(m2));
  __syncthreads();
  if (tid < 3 && sm[tid]) atomicMax(&abits[b*3 + tid], sm[tid]);
}

// per-row contrast factor rf[b,c,h] (reference indexes W columns 0..2 for lum!)
__global__ void k_lum(const float* __restrict__ x, const float* __restrict__ dark,
                      const float* __restrict__ pbuf, const unsigned* __restrict__ abits,
                      float* __restrict__ rf) {
  int gi = blockIdx.x*256 + threadIdx.x;
  if (gi >= NB*NC*NH) return;
  int h = gi & (NH-1);
  int bc = gi >> 9;
  int b = bc/3, c = bc - b*3;
  const float* pb = pbuf + b*32;
  float omega = pb[0], wbp = pb[1+c], g = pb[4], ts = pb[13], cc = pb[14];
  float tone[8];
#pragma unroll
  for (int i = 0; i < 8; i++) tone[i] = pb[5+i];
  float Aval = __uint_as_float(abits[b*3+c]);
  float pt[3];
#pragma unroll
  for (int w = 0; w < 3; w++) {
    float xv = x[(size_t)bc*NHW + (size_t)h*NW + w];
    float dv = dark[(size_t)b*NHW + (size_t)h*NW + w];
    pt[w] = chain_tt(xv, dv, omega, Aval, wbp, g, tone) * ts;
  }
  float lum = fminf(fmaxf(0.27f*pt[0] + 0.67f*pt[1] + 0.06f*pt[2], 0.f), 1.f);
  float cl = 0.5f - 0.5f*cosf(PI_F*lum);
  float fac = (1.f - cc) + cc*cl/(lum + 1e-6f);
  rf[gi] = ts*fac;   // fold tonescale into the row factor
}

// horizontal 25-tap blur of post-contrast image (chain fused on load).
// block = 4 rows x 64 lanes; each lane: 8 staging pixels, 8 outputs. grid (128, 48)
__global__ __launch_bounds__(256) void k_hblur(
    const float* __restrict__ x, const float* __restrict__ dark,
    const float* __restrict__ pbuf, const unsigned* __restrict__ abits,
    const float* __restrict__ rf, const float* __restrict__ gw, float* __restrict__ tmp) {
  __shared__ __align__(16) float pcp[4][544];   // 16 pad | 512 | 16 pad
  int tid = threadIdx.x;
  int row = tid >> 6, lane = tid & 63;
  int bc = blockIdx.y, b = bc/3, c = bc - b*3;
  int h = blockIdx.x*4 + row;
  const float* pb = pbuf + b*32;
  float omega = pb[0], wbp = pb[1+c], g = pb[4];
  float tone[8];
#pragma unroll
  for (int i = 0; i < 8; i++) tone[i] = pb[5+i];
  float Aval = __uint_as_float(abits[b*3+c]);
  float rfv = rf[bc*NH + h];
  if (lane < 16) { pcp[row][lane] = 0.f; pcp[row][528 + lane] = 0.f; }
  const float4* xr = (const float4*)(x + (size_t)bc*NHW + (size_t)h*NW);
  const float4* dr = (const float4*)(dark + (size_t)b*NHW + (size_t)h*NW);
#pragma unroll
  for (int m = 0; m < 2; m++) {
    int i4 = lane + m*64;
    float4 xv = xr[i4], dv = dr[i4], pc;
    pc.x = chain_tt(xv.x, dv.x, omega, Aval, wbp, g, tone)*rfv;
    pc.y = chain_tt(xv.y, dv.y, omega, Aval, wbp, g, tone)*rfv;
    pc.z = chain_tt(xv.z, dv.z, omega, Aval, wbp, g, tone)*rfv;
    pc.w = chain_tt(xv.w, dv.w, omega, Aval, wbp, g, tone)*rfv;
    *(float4*)&pcp[row][16 + i4*4] = pc;
  }
  __syncthreads();
  float kw[25];
#pragma unroll
  for (int j = 0; j < 25; j++) kw[j] = gw[j];
  float acc[8] = {0,0,0,0,0,0,0,0};
  const float* rowp = &pcp[row][lane*8 + 4];   // = (w8-12)+16, 16B aligned
#pragma unroll
  for (int r = 0; r < 8; r++) {
    float4 v = *(const float4*)(rowp + r*4);
    float vs[4] = {v.x, v.y, v.z, v.w};
#pragma unroll
    for (int q = 0; q < 4; q++) {
      int idx = r*4 + q;
#pragma unroll
      for (int i = 0; i < 8; i++) {
        int j = idx - i;
        if (j >= 0 && j < 25) acc[i] = fmaf(kw[j], vs[q], acc[i]);
      }
    }
  }
  float* outr = tmp + (size_t)bc*NHW + (size_t)h*NW + lane*8;
  *(float4*)outr = make_float4(acc[0], acc[1], acc[2], acc[3]);
  *(float4*)(outr+4) = make_float4(acc[4], acc[5], acc[6], acc[7]);
}

// vertical 25-tap blur + center chain recompute + sharpen + sigmoid.
// tile 64w x 128h, block 256 (16 wq x 16 rg, 8 rows each). grid (8, 4, 48)
__global__ __launch_bounds__(256) void k_vblur(
    const float* __restrict__ tmp, const float* __restrict__ x,
    const float* __restrict__ dark, const float* __restrict__ pbuf,
    const unsigned* __restrict__ abits, const float* __restrict__ rf,
    const float* __restrict__ gw, float* __restrict__ out) {
  __shared__ float4 s4[152*16];   // rows h0-12 .. h0+139, 64 cols
  int tid = threadIdx.x;
  int bc = blockIdx.z, b = bc/3, c = bc - b*3;
  int w0 = blockIdx.x*64, h0 = blockIdx.y*128;
  const float* tr = tmp + (size_t)bc*NHW;
  for (int idx = tid; idx < 152*16; idx += 256) {
    int r = idx >> 4, wl4 = idx & 15;
    int gh = h0 - 12 + r;
    float4 v = make_float4(0.f, 0.f, 0.f, 0.f);
    if (gh >= 0 && gh < NH) v = *(const float4*)(tr + (size_t)gh*NW + w0 + wl4*4);
    s4[idx] = v;
  }
  __syncthreads();
  float kw[25];
#pragma unroll
  for (int j = 0; j < 25; j++) kw[j] = gw[j];
  int wq = tid & 15, rg = tid >> 4;
  int rowbase = rg*8;
  float4 acc[8];
#pragma unroll
  for (int i = 0; i < 8; i++) acc[i] = make_float4(0.f, 0.f, 0.f, 0.f);
#pragma unroll
  for (int r = 0; r < 32; r++) {
    float4 v = s4[(rowbase + r)*16 + wq];
#pragma unroll
    for (int i = 0; i < 8; i++) {
      int j = r - i;
      if (j >= 0 && j < 25) {
        float kwj = kw[j];
        acc[i].x = fmaf(kwj, v.x, acc[i].x);
        acc[i].y = fmaf(kwj, v.y, acc[i].y);
        acc[i].z = fmaf(kwj, v.z, acc[i].z);
        acc[i].w = fmaf(kwj, v.w, acc[i].w);
      }
    }
  }
  const float* pb = pbuf + b*32;
  float omega = pb[0], wbp = pb[1+c], g = pb[4], sharp = pb[15];
  float tone[8];
#pragma unroll
  for (int i = 0; i < 8; i++) tone[i] = pb[5+i];
  float Aval = __uint_as_float(abits[b*3+c]);
#pragma unroll
  for (int i = 0; i < 8; i++) {
    int h = h0 + rowbase + i;
    float rfv = rf[bc*NH + h];
    size_t off = (size_t)bc*NHW + (size_t)h*NW + w0 + wq*4;
    float4 xv = *(const float4*)(x + off);
    float4 dv = *(const float4*)(dark + (size_t)b*NHW + (size_t)h*NW + w0 + wq*4);
    float4 o;
    {
      float pc = chain_tt(xv.x, dv.x, omega, Aval, wbp, g, tone)*rfv;
      float res = (pc - acc[i].x)*sharp + pc;
      o.x = 1.f/(1.f + __expf(-res));
    }
    {
      float pc = chain_tt(xv.y, dv.y, omega, Aval, wbp, g, tone)*rfv;
      float res = (pc - acc[i].y)*sharp + pc;
      o.y = 1.f/(1.f + __expf(-res));
    }
    {
      float pc = chain_tt(xv.z, dv.z, omega, Aval, wbp, g, tone)*rfv;
      float res = (pc - acc[i].z)*sharp + pc;
      o.z = 1.f/(1.f + __expf(-res));
    }
    {
      float pc = chain_tt(xv.w, dv.w, omega, Aval, wbp, g, tone)*rfv;
      float res = (pc - acc[i].w)*sharp + pc;
      o.w = 1.f/(1.f + __expf(-res));
    }
    *(float4*)(out + off) = o;
  }
}

extern "C" void kernel_launch(void* const* d_in, const int* in_sizes, int n_in,
                              void* d_out, int out_size, void* d_ws, size_t ws_size,
                              hipStream_t stream) {
  const float* x = (const float*)d_in[0];
  const float* params = (const float*)d_in[1];
  float* out = (float*)d_out;
  float* ws = (float*)d_ws;

  float* dark = ws + DARK_OFF;
  float* tmp  = ws + TMP_OFF;
  unsigned* hist  = (unsigned*)(ws + HIST_OFF);
  unsigned* state = (unsigned*)(ws + STATE_OFF);
  unsigned* abits = (unsigned*)(ws + ABITS_OFF);
  float* pbuf = ws + PBUF_OFF;
  float* gw   = ws + GW_OFF;
  float* rf   = ws + RF_OFF;

  k_params<<<1, 256, 0, stream>>>(params, pbuf, gw, hist, abits);
  k_dark<<<dim3(NHW/2048, NB), 256, 0, stream>>>(x, dark, hist);
  k_scan<<<NB, 64, 0, stream>>>(hist, state, 0);
  for (int lvl = 1; lvl <= 3; lvl++) {
    k_hist<<<dim3(NHW/4096, NB), 256, 0, stream>>>((const unsigned*)dark, hist, state, lvl);
    k_scan<<<NB, 64, 0, stream>>>(hist, state, lvl);
  }
  k_amax<<<dim3(NHW/2048, NB), 256, 0, stream>>>(x, dark, state, abits);
  k_lum<<<(NB*NC*NH + 255)/256, 256, 0, stream>>>(x, dark, pbuf, abits, rf);
  k_hblur<<<dim3(NH/4, NB*NC), 256, 0, stream>>>(x, dark, pbuf, abits, rf, gw, tmp);
  k_vblur<<<dim3(NW/64, NH/128, NB*NC), 256, 0, stream>>>(tmp, x, dark, pbuf, abits, rf, gw, out);
}

// Round 3
// 212.981 us; speedup vs baseline: 1.3823x; 1.3823x over previous
//
#include <hip/hip_runtime.h>
#include <math.h>

#define NB 16
#define NC 3
#define NH 512
#define NW 512
#define NHW (NH*NW)
#define KSEL 26214u
#define PI_F 3.14159265358979f

// ---- ws layout (float units) ----
#define DARK_OFF   0
#define TMP_OFF    (NB*NHW)                  // 4,194,304
#define HIST_OFF   (TMP_OFF + NB*NC*NHW)     // 16,777,216
#define STATE_OFF  (HIST_OFF + NB*256)
#define ABITS_OFF  (STATE_OFF + NB*4)
#define PBUF_OFF   (ABITS_OFF + NB*3)
#define GW_OFF     (PBUF_OFF + NB*32)
#define RF_OFF     (GW_OFF + 32)
// total ~16.81M floats ~= 67.3 MB of ws

__device__ __forceinline__ float fast_rcp(float x) { return __builtin_amdgcn_rcpf(x); }
__device__ __forceinline__ float fast_exp2(float x) { return __builtin_amdgcn_exp2f(x); }
__device__ __forceinline__ float fast_log2(float x) { return __builtin_amdgcn_logf(x); }

// pointwise chain through tone (pre tone-scale): defog -> wb -> gamma -> tone
// All-native math: v_rcp (1 ULP), v_exp/v_log (native). Error << 2e-2 tol.
__device__ __forceinline__ float chain_tt(float xv, float dv, float omega, float Aval,
                                          float wbp, float g, const float* tone) {
  float t = fminf(fmaxf(1.f - omega*dv, 0.1f), 1.f);
  float J = (xv - Aval)*fast_rcp(t) + Aval;
  J = fminf(fmaxf(J, 0.f), 1.f);
  float v = J * wbp;
  float u = fast_exp2(g * fast_log2(fmaxf(v, 1e-4f)));   // pow(v,g), native
  float tt = 0.f;
#pragma unroll
  for (int i = 0; i < 8; i++)
    tt = fmaf(fminf(fmaxf(u - 0.125f*(float)i, 0.f), 0.125f), tone[i], tt);
  return tt;
}

// K1: parse params, build gaussian weights, zero hist + A
__global__ void k_params(const float* __restrict__ p, float* __restrict__ pbuf,
                         float* __restrict__ gw, unsigned* __restrict__ hist,
                         unsigned* __restrict__ abits) {
  int tid = threadIdx.x;
  if (tid < NB) {
    const float* pp = p + tid*15;
    float* ob = pbuf + tid*32;
    float omega = (tanhf(pp[0])+1.f)*0.5f*0.9f + 0.1f;
    float wb0 = 1.0f;  // mask=0 -> tanh01(0)*1-0.5=0 -> exp(0)=1
    float wb1 = expf((tanhf(pp[2])+1.f)*0.5f - 0.5f);
    float wb2 = expf((tanhf(pp[3])+1.f)*0.5f - 0.5f);
    float denom = 0.27f*wb0 + 0.67f*wb1 + 0.06f*wb2 + 1e-5f;
    float lg = logf(3.0f);
    float g = expf((tanhf(pp[4])+1.f)*0.5f*(2.f*lg) - lg);
    float ts = 0.f, tone[8];
    for (int i = 0; i < 8; i++) { tone[i] = (tanhf(pp[5+i])+1.f)*0.5f*1.5f + 0.5f; ts += tone[i]; }
    ts += 1e-30f;
    ob[0] = omega; ob[1] = wb0/denom; ob[2] = wb1/denom; ob[3] = wb2/denom; ob[4] = g;
    for (int i = 0; i < 8; i++) ob[5+i] = tone[i];
    ob[13] = 8.0f/ts;            // tonescale
    ob[14] = tanhf(pp[13]);      // contrast c
    ob[15] = (tanhf(pp[14])+1.f)*0.5f*5.0f;  // sharpen
  }
  if (tid == 32) {
    float wv[25], wsum = 0.f;
    for (int i = 0; i < 25; i++) { float d = (float)(i-12)/5.0f; wv[i] = expf(-0.5f*d*d); wsum += wv[i]; }
    for (int i = 0; i < 25; i++) gw[i] = wv[i]/wsum;
  }
  for (int i = tid; i < NB*256; i += blockDim.x) hist[i] = 0u;
  if (tid < NB*3) abits[tid] = 0u;
}

// K2: dark channel + level-0 radix histogram (top byte). grid (128, NB) x 256
__global__ void k_dark(const float* __restrict__ x, float* __restrict__ dark,
                       unsigned* __restrict__ hist) {
  __shared__ unsigned lh[8*256];
  int tid = threadIdx.x, b = blockIdx.y;
  for (int i = tid; i < 8*256; i += 256) lh[i] = 0u;
  __syncthreads();
  const float4* x0 = (const float4*)(x + (size_t)b*NC*NHW);
  const float4* x1 = x0 + NHW/4;
  const float4* x2 = x1 + NHW/4;
  float4* d4 = (float4*)(dark + (size_t)b*NHW);
  unsigned* lhm = lh + (tid & 7)*256;
  int base = blockIdx.x*512 + tid;
#pragma unroll
  for (int it = 0; it < 2; it++) {
    int i = base + it*256;
    float4 a = x0[i], g = x1[i], r = x2[i];
    float4 d;
    d.x = fminf(fminf(a.x,g.x),r.x); d.y = fminf(fminf(a.y,g.y),r.y);
    d.z = fminf(fminf(a.z,g.z),r.z); d.w = fminf(fminf(a.w,g.w),r.w);
    d4[i] = d;
    atomicAdd(&lhm[__float_as_uint(d.x)>>24], 1u);
    atomicAdd(&lhm[__float_as_uint(d.y)>>24], 1u);
    atomicAdd(&lhm[__float_as_uint(d.z)>>24], 1u);
    atomicAdd(&lhm[__float_as_uint(d.w)>>24], 1u);
  }
  __syncthreads();
  unsigned s = 0;
  for (int r = 0; r < 8; r++) s += lh[r*256 + tid];
  if (s) atomicAdd(&hist[b*256 + tid], s);
}

// scan one radix level: find bin containing k-th largest, update state, zero hist
__global__ void k_scan(unsigned* __restrict__ hist, unsigned* __restrict__ state, int level) {
  int b = blockIdx.x, lane = threadIdx.x;  // 64 threads = 1 wave
  unsigned cnt[4], s = 0;
#pragma unroll
  for (int j = 0; j < 4; j++) { cnt[j] = hist[b*256 + (255 - (lane*4+j))]; s += cnt[j]; }
  unsigned inc = s;
  for (int off = 1; off < 64; off <<= 1) {
    unsigned n = __shfl_up(inc, off);
    if (lane >= off) inc += n;
  }
  unsigned excl = inc - s;
  unsigned k = (level == 0) ? KSEL : state[b*4+1];
  if (excl < k && k <= inc) {
    unsigned run = excl, rem = 0; int binj = -1;
#pragma unroll
    for (int j = 0; j < 4; j++) {
      unsigned nb = run + cnt[j];
      if (binj < 0 && k <= nb) { binj = j; rem = k - run; }
      run = nb;
    }
    unsigned bin = 255u - (unsigned)(lane*4 + binj);
    int shift = 24 - 8*level;
    unsigned prefix = ((level == 0) ? 0u : state[b*4+0]) | (bin << shift);
    state[b*4+0] = prefix; state[b*4+1] = rem;
    if (level == 3) state[b*4+2] = prefix;   // exact tau bits
  }
#pragma unroll
  for (int i = 0; i < 4; i++) hist[b*256 + lane*4 + i] = 0u;
}

// radix refine levels 1..3 over dark bits. grid (64, NB) x 256
__global__ void k_hist(const unsigned* __restrict__ darkbits, unsigned* __restrict__ hist,
                       const unsigned* __restrict__ state, int level) {
  __shared__ unsigned lh[256];
  int tid = threadIdx.x, b = blockIdx.y;
  lh[tid] = 0u;
  __syncthreads();
  int shift = 24 - 8*level;
  unsigned mask = ~((1u << (shift+8)) - 1u);
  unsigned prefix = state[b*4];
  const uint4* dp = (const uint4*)(darkbits + (size_t)b*NHW);
  int base = blockIdx.x*1024 + tid;
#pragma unroll
  for (int it = 0; it < 4; it++) {
    uint4 u = dp[base + it*256];
    if ((u.x & mask) == prefix) atomicAdd(&lh[(u.x>>shift)&0xFF], 1u);
    if ((u.y & mask) == prefix) atomicAdd(&lh[(u.y>>shift)&0xFF], 1u);
    if ((u.z & mask) == prefix) atomicAdd(&lh[(u.z>>shift)&0xFF], 1u);
    if ((u.w & mask) == prefix) atomicAdd(&lh[(u.w>>shift)&0xFF], 1u);
  }
  __syncthreads();
  if (lh[tid]) atomicAdd(&hist[b*256 + tid], lh[tid]);
}

// A[b,c] = max x[b,c,p] over pixels with dark >= tau. grid (128, NB) x 256
__global__ void k_amax(const float* __restrict__ x, const float* __restrict__ dark,
                       const unsigned* __restrict__ state, unsigned* __restrict__ abits) {
  __shared__ unsigned sm[3];
  int tid = threadIdx.x, b = blockIdx.y;
  if (tid < 3) sm[tid] = 0u;
  __syncthreads();
  float tau = __uint_as_float(state[b*4+2]);
  const float4* x0 = (const float4*)(x + (size_t)b*NC*NHW);
  const float4* x1 = x0 + NHW/4;
  const float4* x2 = x1 + NHW/4;
  const float4* dp = (const float4*)(dark + (size_t)b*NHW);
  float m0 = 0.f, m1 = 0.f, m2 = 0.f;
  int base = blockIdx.x*512 + tid;
#pragma unroll
  for (int it = 0; it < 2; it++) {
    int i = base + it*256;
    float4 d = dp[i];
    bool s0 = d.x >= tau, s1 = d.y >= tau, s2 = d.z >= tau, s3 = d.w >= tau;
    if (s0 | s1 | s2 | s3) {
      float4 a = x0[i], g = x1[i], r = x2[i];
      if (s0) { m0 = fmaxf(m0,a.x); m1 = fmaxf(m1,g.x); m2 = fmaxf(m2,r.x); }
      if (s1) { m0 = fmaxf(m0,a.y); m1 = fmaxf(m1,g.y); m2 = fmaxf(m2,r.y); }
      if (s2) { m0 = fmaxf(m0,a.z); m1 = fmaxf(m1,g.z); m2 = fmaxf(m2,r.z); }
      if (s3) { m0 = fmaxf(m0,a.w); m1 = fmaxf(m1,g.w); m2 = fmaxf(m2,r.w); }
    }
  }
  atomicMax(&sm[0], __float_as_uint(m0));
  atomicMax(&sm[1], __float_as_uint(m1));
  atomicMax(&sm[2], __float_as_uint(m2));
  __syncthreads();
  if (tid < 3 && sm[tid]) atomicMax(&abits[b*3 + tid], sm[tid]);
}

// per-row contrast factor rf[b,c,h] (reference indexes W columns 0..2 for lum!)
__global__ void k_lum(const float* __restrict__ x, const float* __restrict__ dark,
                      const float* __restrict__ pbuf, const unsigned* __restrict__ abits,
                      float* __restrict__ rf) {
  int gi = blockIdx.x*256 + threadIdx.x;
  if (gi >= NB*NC*NH) return;
  int h = gi & (NH-1);
  int bc = gi >> 9;
  int b = bc/3, c = bc - b*3;
  const float* pb = pbuf + b*32;
  float omega = pb[0], wbp = pb[1+c], g = pb[4], ts = pb[13], cc = pb[14];
  float tone[8];
#pragma unroll
  for (int i = 0; i < 8; i++) tone[i] = pb[5+i];
  float Aval = __uint_as_float(abits[b*3+c]);
  float pt[3];
#pragma unroll
  for (int w = 0; w < 3; w++) {
    float xv = x[(size_t)bc*NHW + (size_t)h*NW + w];
    float dv = dark[(size_t)b*NHW + (size_t)h*NW + w];
    pt[w] = chain_tt(xv, dv, omega, Aval, wbp, g, tone) * ts;
  }
  float lum = fminf(fmaxf(0.27f*pt[0] + 0.67f*pt[1] + 0.06f*pt[2], 0.f), 1.f);
  float cl = 0.5f - 0.5f*__cosf(PI_F*lum);
  float fac = (1.f - cc) + cc*cl*fast_rcp(lum + 1e-6f);
  rf[gi] = ts*fac;   // fold tonescale into the row factor
}

// horizontal 25-tap blur of post-contrast image (chain fused on load).
// block = 4 rows x 64 lanes; each lane: 8 staging pixels, 8 outputs. grid (128, 48)
__global__ __launch_bounds__(256) void k_hblur(
    const float* __restrict__ x, const float* __restrict__ dark,
    const float* __restrict__ pbuf, const unsigned* __restrict__ abits,
    const float* __restrict__ rf, const float* __restrict__ gw, float* __restrict__ tmp) {
  __shared__ __align__(16) float pcp[4][544];   // 16 pad | 512 | 16 pad
  int tid = threadIdx.x;
  int row = tid >> 6, lane = tid & 63;
  int bc = blockIdx.y, b = bc/3, c = bc - b*3;
  int h = blockIdx.x*4 + row;
  const float* pb = pbuf + b*32;
  float omega = pb[0], wbp = pb[1+c], g = pb[4];
  float tone[8];
#pragma unroll
  for (int i = 0; i < 8; i++) tone[i] = pb[5+i];
  float Aval = __uint_as_float(abits[b*3+c]);
  float rfv = rf[bc*NH + h];
  if (lane < 16) { pcp[row][lane] = 0.f; pcp[row][528 + lane] = 0.f; }
  const float4* xr = (const float4*)(x + (size_t)bc*NHW + (size_t)h*NW);
  const float4* dr = (const float4*)(dark + (size_t)b*NHW + (size_t)h*NW);
#pragma unroll
  for (int m = 0; m < 2; m++) {
    int i4 = lane + m*64;
    float4 xv = xr[i4], dv = dr[i4], pc;
    pc.x = chain_tt(xv.x, dv.x, omega, Aval, wbp, g, tone)*rfv;
    pc.y = chain_tt(xv.y, dv.y, omega, Aval, wbp, g, tone)*rfv;
    pc.z = chain_tt(xv.z, dv.z, omega, Aval, wbp, g, tone)*rfv;
    pc.w = chain_tt(xv.w, dv.w, omega, Aval, wbp, g, tone)*rfv;
    *(float4*)&pcp[row][16 + i4*4] = pc;
  }
  __syncthreads();
  float kw[25];
#pragma unroll
  for (int j = 0; j < 25; j++) kw[j] = gw[j];
  float acc[8] = {0,0,0,0,0,0,0,0};
  const float* rowp = &pcp[row][lane*8 + 4];   // = (w8-12)+16, 16B aligned
#pragma unroll
  for (int r = 0; r < 8; r++) {
    float4 v = *(const float4*)(rowp + r*4);
    float vs[4] = {v.x, v.y, v.z, v.w};
#pragma unroll
    for (int q = 0; q < 4; q++) {
      int idx = r*4 + q;
#pragma unroll
      for (int i = 0; i < 8; i++) {
        int j = idx - i;
        if (j >= 0 && j < 25) acc[i] = fmaf(kw[j], vs[q], acc[i]);
      }
    }
  }
  float* outr = tmp + (size_t)bc*NHW + (size_t)h*NW + lane*8;
  *(float4*)outr = make_float4(acc[0], acc[1], acc[2], acc[3]);
  *(float4*)(outr+4) = make_float4(acc[4], acc[5], acc[6], acc[7]);
}

// vertical 25-tap blur + center chain recompute + sharpen + sigmoid.
// tile 64w x 128h, block 256 (16 wq x 16 rg, 8 rows each). grid (8, 4, 48)
__global__ __launch_bounds__(256) void k_vblur(
    const float* __restrict__ tmp, const float* __restrict__ x,
    const float* __restrict__ dark, const float* __restrict__ pbuf,
    const unsigned* __restrict__ abits, const float* __restrict__ rf,
    const float* __restrict__ gw, float* __restrict__ out) {
  __shared__ float4 s4[152*16];   // rows h0-12 .. h0+139, 64 cols
  int tid = threadIdx.x;
  int bc = blockIdx.z, b = bc/3, c = bc - b*3;
  int w0 = blockIdx.x*64, h0 = blockIdx.y*128;
  const float* tr = tmp + (size_t)bc*NHW;
  for (int idx = tid; idx < 152*16; idx += 256) {
    int r = idx >> 4, wl4 = idx & 15;
    int gh = h0 - 12 + r;
    float4 v = make_float4(0.f, 0.f, 0.f, 0.f);
    if (gh >= 0 && gh < NH) v = *(const float4*)(tr + (size_t)gh*NW + w0 + wl4*4);
    s4[idx] = v;
  }
  __syncthreads();
  float kw[25];
#pragma unroll
  for (int j = 0; j < 25; j++) kw[j] = gw[j];
  int wq = tid & 15, rg = tid >> 4;
  int rowbase = rg*8;
  float4 acc[8];
#pragma unroll
  for (int i = 0; i < 8; i++) acc[i] = make_float4(0.f, 0.f, 0.f, 0.f);
#pragma unroll
  for (int r = 0; r < 32; r++) {
    float4 v = s4[(rowbase + r)*16 + wq];
#pragma unroll
    for (int i = 0; i < 8; i++) {
      int j = r - i;
      if (j >= 0 && j < 25) {
        float kwj = kw[j];
        acc[i].x = fmaf(kwj, v.x, acc[i].x);
        acc[i].y = fmaf(kwj, v.y, acc[i].y);
        acc[i].z = fmaf(kwj, v.z, acc[i].z);
        acc[i].w = fmaf(kwj, v.w, acc[i].w);
      }
    }
  }
  const float* pb = pbuf + b*32;
  float omega = pb[0], wbp = pb[1+c], g = pb[4], sharp = pb[15];
  float tone[8];
#pragma unroll
  for (int i = 0; i < 8; i++) tone[i] = pb[5+i];
  float Aval = __uint_as_float(abits[b*3+c]);
#pragma unroll
  for (int i = 0; i < 8; i++) {
    int h = h0 + rowbase + i;
    float rfv = rf[bc*NH + h];
    size_t off = (size_t)bc*NHW + (size_t)h*NW + w0 + wq*4;
    float4 xv = *(const float4*)(x + off);
    float4 dv = *(const float4*)(dark + (size_t)b*NHW + (size_t)h*NW + w0 + wq*4);
    float4 o;
    {
      float pc = chain_tt(xv.x, dv.x, omega, Aval, wbp, g, tone)*rfv;
      float res = (pc - acc[i].x)*sharp + pc;
      o.x = fast_rcp(1.f + __expf(-res));
    }
    {
      float pc = chain_tt(xv.y, dv.y, omega, Aval, wbp, g, tone)*rfv;
      float res = (pc - acc[i].y)*sharp + pc;
      o.y = fast_rcp(1.f + __expf(-res));
    }
    {
      float pc = chain_tt(xv.z, dv.z, omega, Aval, wbp, g, tone)*rfv;
      float res = (pc - acc[i].z)*sharp + pc;
      o.z = fast_rcp(1.f + __expf(-res));
    }
    {
      float pc = chain_tt(xv.w, dv.w, omega, Aval, wbp, g, tone)*rfv;
      float res = (pc - acc[i].w)*sharp + pc;
      o.w = fast_rcp(1.f + __expf(-res));
    }
    *(float4*)(out + off) = o;
  }
}

extern "C" void kernel_launch(void* const* d_in, const int* in_sizes, int n_in,
                              void* d_out, int out_size, void* d_ws, size_t ws_size,
                              hipStream_t stream) {
  const float* x = (const float*)d_in[0];
  const float* params = (const float*)d_in[1];
  float* out = (float*)d_out;
  float* ws = (float*)d_ws;

  float* dark = ws + DARK_OFF;
  float* tmp  = ws + TMP_OFF;
  unsigned* hist  = (unsigned*)(ws + HIST_OFF);
  unsigned* state = (unsigned*)(ws + STATE_OFF);
  unsigned* abits = (unsigned*)(ws + ABITS_OFF);
  float* pbuf = ws + PBUF_OFF;
  float* gw   = ws + GW_OFF;
  float* rf   = ws + RF_OFF;

  k_params<<<1, 256, 0, stream>>>(params, pbuf, gw, hist, abits);
  k_dark<<<dim3(NHW/2048, NB), 256, 0, stream>>>(x, dark, hist);
  k_scan<<<NB, 64, 0, stream>>>(hist, state, 0);
  for (int lvl = 1; lvl <= 3; lvl++) {
    k_hist<<<dim3(NHW/4096, NB), 256, 0, stream>>>((const unsigned*)dark, hist, state, lvl);
    k_scan<<<NB, 64, 0, stream>>>(hist, state, lvl);
  }
  k_amax<<<dim3(NHW/2048, NB), 256, 0, stream>>>(x, dark, state, abits);
  k_lum<<<(NB*NC*NH + 255)/256, 256, 0, stream>>>(x, dark, pbuf, abits, rf);
  k_hblur<<<dim3(NH/4, NB*NC), 256, 0, stream>>>(x, dark, pbuf, abits, rf, gw, tmp);
  k_vblur<<<dim3(NW/64, NH/128, NB*NC), 256, 0, stream>>>(tmp, x, dark, pbuf, abits, rf, gw, out);
}

// Round 4
// 178.915 us; speedup vs baseline: 1.6454x; 1.1904x over previous
//
#include <hip/hip_runtime.h>
#include <math.h>

#define NB 16
#define NC 3
#define NH 512
#define NW 512
#define NHW (NH*NW)
#define KSEL 26214u
#define PI_F 3.14159265358979f
#define LOG2E_F 1.44269504f

typedef _Float16 half4v __attribute__((ext_vector_type(4)));
typedef _Float16 half8v __attribute__((ext_vector_type(8)));
typedef float    float4v __attribute__((ext_vector_type(4)));

// ---- ws layout (float units) ----
#define DARK_OFF   0                              // NB*NHW fp32
#define TMPH_OFF   (NB*NHW)                       // NB*NC*NHW fp16 (blurred-H)
#define PCH_OFF    (TMPH_OFF + NB*NC*NHW/2)       // NB*NC*NHW fp16 (post-contrast)
#define HIST_OFF   (PCH_OFF + NB*NC*NHW/2)
#define STATE_OFF  (HIST_OFF + NB*256)
#define ABITS_OFF  (STATE_OFF + NB*4)
#define PBUF_OFF   (ABITS_OFF + NB*3)
#define GW_OFF     (PBUF_OFF + NB*32)
// total ~16.8M floats ~= 67 MB of ws (ws is 256 MB)

__device__ __forceinline__ float fast_rcp(float x)  { return __builtin_amdgcn_rcpf(x); }
__device__ __forceinline__ float fast_exp2(float x) { return __builtin_amdgcn_exp2f(x); }
__device__ __forceinline__ float fast_log2(float x) { return __builtin_amdgcn_logf(x); }

// pointwise chain through tone (pre contrast-scale): defog -> wb -> gamma -> tone
__device__ __forceinline__ float chain_tt(float xv, float dv, float omega, float Aval,
                                          float wbp, float g, const float* tone) {
  float t = fminf(fmaxf(1.f - omega*dv, 0.1f), 1.f);
  float J = (xv - Aval)*fast_rcp(t) + Aval;
  J = fminf(fmaxf(J, 0.f), 1.f);
  float v = J * wbp;
  float u = fast_exp2(g * fast_log2(fmaxf(v, 1e-4f)));   // pow(v,g), native
  float tt = 0.f;
#pragma unroll
  for (int i = 0; i < 8; i++)
    tt = fmaf(fminf(fmaxf(u - 0.125f*(float)i, 0.f), 0.125f), tone[i], tt);
  return tt;
}

// K1: parse params, build gaussian weights, zero hist + A
__global__ void k_params(const float* __restrict__ p, float* __restrict__ pbuf,
                         float* __restrict__ gw, unsigned* __restrict__ hist,
                         unsigned* __restrict__ abits) {
  int tid = threadIdx.x;
  if (tid < NB) {
    const float* pp = p + tid*15;
    float* ob = pbuf + tid*32;
    float omega = (tanhf(pp[0])+1.f)*0.5f*0.9f + 0.1f;
    float wb0 = 1.0f;  // mask=0 -> exp(0)=1
    float wb1 = expf((tanhf(pp[2])+1.f)*0.5f - 0.5f);
    float wb2 = expf((tanhf(pp[3])+1.f)*0.5f - 0.5f);
    float denom = 0.27f*wb0 + 0.67f*wb1 + 0.06f*wb2 + 1e-5f;
    float lg = logf(3.0f);
    float g = expf((tanhf(pp[4])+1.f)*0.5f*(2.f*lg) - lg);
    float ts = 0.f, tone[8];
    for (int i = 0; i < 8; i++) { tone[i] = (tanhf(pp[5+i])+1.f)*0.5f*1.5f + 0.5f; ts += tone[i]; }
    ts += 1e-30f;
    ob[0] = omega; ob[1] = wb0/denom; ob[2] = wb1/denom; ob[3] = wb2/denom; ob[4] = g;
    for (int i = 0; i < 8; i++) ob[5+i] = tone[i];
    ob[13] = 8.0f/ts;            // tonescale
    ob[14] = tanhf(pp[13]);      // contrast c
    ob[15] = (tanhf(pp[14])+1.f)*0.5f*5.0f;  // sharpen
  }
  if (tid == 32) {
    float wv[25], wsum = 0.f;
    for (int i = 0; i < 25; i++) { float d = (float)(i-12)/5.0f; wv[i] = expf(-0.5f*d*d); wsum += wv[i]; }
    for (int i = 0; i < 25; i++) gw[i] = wv[i]/wsum;
  }
  for (int i = tid; i < NB*256; i += blockDim.x) hist[i] = 0u;
  if (tid < NB*3) abits[tid] = 0u;
}

// K2: dark channel + level-0 radix histogram (top byte). grid (128, NB) x 256
__global__ void k_dark(const float* __restrict__ x, float* __restrict__ dark,
                       unsigned* __restrict__ hist) {
  __shared__ unsigned lh[8*256];
  int tid = threadIdx.x, b = blockIdx.y;
  for (int i = tid; i < 8*256; i += 256) lh[i] = 0u;
  __syncthreads();
  const float4* x0 = (const float4*)(x + (size_t)b*NC*NHW);
  const float4* x1 = x0 + NHW/4;
  const float4* x2 = x1 + NHW/4;
  float4* d4 = (float4*)(dark + (size_t)b*NHW);
  unsigned* lhm = lh + (tid & 7)*256;
  int base = blockIdx.x*512 + tid;
#pragma unroll
  for (int it = 0; it < 2; it++) {
    int i = base + it*256;
    float4 a = x0[i], g = x1[i], r = x2[i];
    float4 d;
    d.x = fminf(fminf(a.x,g.x),r.x); d.y = fminf(fminf(a.y,g.y),r.y);
    d.z = fminf(fminf(a.z,g.z),r.z); d.w = fminf(fminf(a.w,g.w),r.w);
    d4[i] = d;
    atomicAdd(&lhm[__float_as_uint(d.x)>>24], 1u);
    atomicAdd(&lhm[__float_as_uint(d.y)>>24], 1u);
    atomicAdd(&lhm[__float_as_uint(d.z)>>24], 1u);
    atomicAdd(&lhm[__float_as_uint(d.w)>>24], 1u);
  }
  __syncthreads();
  unsigned s = 0;
  for (int r = 0; r < 8; r++) s += lh[r*256 + tid];
  if (s) atomicAdd(&hist[b*256 + tid], s);
}

// scan one radix level: find bin holding k-th largest, update state, zero hist.
// After level 1 we stop: tau = 16-bit-prefix lower bound (superset select;
// A shifts by <1e-6 — see analysis).
__global__ void k_scan(unsigned* __restrict__ hist, unsigned* __restrict__ state, int level) {
  int b = blockIdx.x, lane = threadIdx.x;  // 64 threads = 1 wave
  unsigned cnt[4], s = 0;
#pragma unroll
  for (int j = 0; j < 4; j++) { cnt[j] = hist[b*256 + (255 - (lane*4+j))]; s += cnt[j]; }
  unsigned inc = s;
  for (int off = 1; off < 64; off <<= 1) {
    unsigned n = __shfl_up(inc, off);
    if (lane >= off) inc += n;
  }
  unsigned excl = inc - s;
  unsigned k = (level == 0) ? KSEL : state[b*4+1];
  if (excl < k && k <= inc) {
    unsigned run = excl, rem = 0; int binj = -1;
#pragma unroll
    for (int j = 0; j < 4; j++) {
      unsigned nb = run + cnt[j];
      if (binj < 0 && k <= nb) { binj = j; rem = k - run; }
      run = nb;
    }
    unsigned bin = 255u - (unsigned)(lane*4 + binj);
    int shift = 24 - 8*level;
    unsigned prefix = ((level == 0) ? 0u : state[b*4+0]) | (bin << shift);
    state[b*4+0] = prefix; state[b*4+1] = rem;
    if (level == 1) state[b*4+2] = prefix;   // tau lower bound (16-bit prefix)
  }
#pragma unroll
  for (int i = 0; i < 4; i++) hist[b*256 + lane*4 + i] = 0u;
}

// radix refine level 1 over dark bits. grid (64, NB) x 256
__global__ void k_hist(const unsigned* __restrict__ darkbits, unsigned* __restrict__ hist,
                       const unsigned* __restrict__ state, int level) {
  __shared__ unsigned lh[256];
  int tid = threadIdx.x, b = blockIdx.y;
  lh[tid] = 0u;
  __syncthreads();
  int shift = 24 - 8*level;
  unsigned mask = ~((1u << (shift+8)) - 1u);
  unsigned prefix = state[b*4];
  const uint4* dp = (const uint4*)(darkbits + (size_t)b*NHW);
  int base = blockIdx.x*1024 + tid;
#pragma unroll
  for (int it = 0; it < 4; it++) {
    uint4 u = dp[base + it*256];
    if ((u.x & mask) == prefix) atomicAdd(&lh[(u.x>>shift)&0xFF], 1u);
    if ((u.y & mask) == prefix) atomicAdd(&lh[(u.y>>shift)&0xFF], 1u);
    if ((u.z & mask) == prefix) atomicAdd(&lh[(u.z>>shift)&0xFF], 1u);
    if ((u.w & mask) == prefix) atomicAdd(&lh[(u.w>>shift)&0xFF], 1u);
  }
  __syncthreads();
  if (lh[tid]) atomicAdd(&hist[b*256 + tid], lh[tid]);
}

// A[b,c] = max x[b,c,p] over pixels with dark >= tau. grid (128, NB) x 256
__global__ void k_amax(const float* __restrict__ x, const float* __restrict__ dark,
                       const unsigned* __restrict__ state, unsigned* __restrict__ abits) {
  __shared__ unsigned sm[3];
  int tid = threadIdx.x, b = blockIdx.y;
  if (tid < 3) sm[tid] = 0u;
  __syncthreads();
  float tau = __uint_as_float(state[b*4+2]);
  const float4* x0 = (const float4*)(x + (size_t)b*NC*NHW);
  const float4* x1 = x0 + NHW/4;
  const float4* x2 = x1 + NHW/4;
  const float4* dp = (const float4*)(dark + (size_t)b*NHW);
  float m0 = 0.f, m1 = 0.f, m2 = 0.f;
  int base = blockIdx.x*512 + tid;
#pragma unroll
  for (int it = 0; it < 2; it++) {
    int i = base + it*256;
    float4 d = dp[i];
    bool s0 = d.x >= tau, s1 = d.y >= tau, s2 = d.z >= tau, s3 = d.w >= tau;
    if (s0 | s1 | s2 | s3) {
      float4 a = x0[i], g = x1[i], r = x2[i];
      if (s0) { m0 = fmaxf(m0,a.x); m1 = fmaxf(m1,g.x); m2 = fmaxf(m2,r.x); }
      if (s1) { m0 = fmaxf(m0,a.y); m1 = fmaxf(m1,g.y); m2 = fmaxf(m2,r.y); }
      if (s2) { m0 = fmaxf(m0,a.z); m1 = fmaxf(m1,g.z); m2 = fmaxf(m2,r.z); }
      if (s3) { m0 = fmaxf(m0,a.w); m1 = fmaxf(m1,g.w); m2 = fmaxf(m2,r.w); }
    }
  }
  atomicMax(&sm[0], __float_as_uint(m0));
  atomicMax(&sm[1], __float_as_uint(m1));
  atomicMax(&sm[2], __float_as_uint(m2));
  __syncthreads();
  if (tid < 3 && sm[tid]) atomicMax(&abits[b*3 + tid], sm[tid]);
}

// horizontal 25-tap blur; chain fused on load, per-row contrast factor computed
// in-block (needs only cols 0..2, already staged). Writes blurred row (tmp, fp16)
// AND post-contrast center (pc, fp16). block = 4 rows x 64 lanes. grid (128, 48)
__global__ __launch_bounds__(256) void k_hblur(
    const float* __restrict__ x, const float* __restrict__ dark,
    const float* __restrict__ pbuf, const unsigned* __restrict__ abits,
    const float* __restrict__ gw, _Float16* __restrict__ tmph,
    _Float16* __restrict__ pch) {
  __shared__ __align__(16) float pcp[4][544];   // 16 pad | 512 | 16 pad (pre-rf chain)
  __shared__ float rfs[4];
  int tid = threadIdx.x;
  int row = tid >> 6, lane = tid & 63;
  int bc = blockIdx.y, b = bc/3, c = bc - b*3;
  int h = blockIdx.x*4 + row;
  const float* pb = pbuf + b*32;
  float omega = pb[0], wbp = pb[1+c], g = pb[4], ts = pb[13], cc = pb[14];
  float tone[8];
#pragma unroll
  for (int i = 0; i < 8; i++) tone[i] = pb[5+i];
  float Aval = __uint_as_float(abits[b*3+c]);
  if (lane < 16) { pcp[row][lane] = 0.f; pcp[row][528 + lane] = 0.f; }
  const float4* xr = (const float4*)(x + (size_t)bc*NHW + (size_t)h*NW);
  const float4* dr = (const float4*)(dark + (size_t)b*NHW + (size_t)h*NW);
#pragma unroll
  for (int m = 0; m < 2; m++) {
    int i4 = lane + m*64;
    float4 xv = xr[i4], dv = dr[i4], pc;
    pc.x = chain_tt(xv.x, dv.x, omega, Aval, wbp, g, tone);
    pc.y = chain_tt(xv.y, dv.y, omega, Aval, wbp, g, tone);
    pc.z = chain_tt(xv.z, dv.z, omega, Aval, wbp, g, tone);
    pc.w = chain_tt(xv.w, dv.w, omega, Aval, wbp, g, tone);
    *(float4*)&pcp[row][16 + i4*4] = pc;
  }
  __syncthreads();
  if (lane == 0) {
    // contrast lum uses W-columns 0..2 (reference indexes image[:,:,:,0..2])
    float p0 = pcp[row][16]*ts, p1 = pcp[row][17]*ts, p2 = pcp[row][18]*ts;
    float lum = fminf(fmaxf(0.27f*p0 + 0.67f*p1 + 0.06f*p2, 0.f), 1.f);
    float cl = 0.5f - 0.5f*__cosf(PI_F*lum);
    rfs[row] = ts*((1.f - cc) + cc*cl*fast_rcp(lum + 1e-6f));
  }
  __syncthreads();
  float rfv = rfs[row];
  float kw[25];
#pragma unroll
  for (int j = 0; j < 25; j++) kw[j] = gw[j];
  float acc[8] = {0,0,0,0,0,0,0,0};
  const float* rowp = &pcp[row][lane*8 + 4];
#pragma unroll
  for (int r = 0; r < 8; r++) {
    float4 v = *(const float4*)(rowp + r*4);
    float vs[4] = {v.x, v.y, v.z, v.w};
#pragma unroll
    for (int q = 0; q < 4; q++) {
      int idx = r*4 + q;
#pragma unroll
      for (int i = 0; i < 8; i++) {
        int j = idx - i;
        if (j >= 0 && j < 25) acc[i] = fmaf(kw[j], vs[q], acc[i]);
      }
    }
  }
  size_t off = (size_t)bc*NHW + (size_t)h*NW + lane*8;
  half8v th;
#pragma unroll
  for (int i = 0; i < 8; i++) th[i] = (_Float16)(acc[i]*rfv);
  *(half8v*)(tmph + off) = th;
  float4 c0 = *(float4*)&pcp[row][16 + lane*8];
  float4 c1 = *(float4*)&pcp[row][20 + lane*8];
  half8v ph;
  ph[0] = (_Float16)(c0.x*rfv); ph[1] = (_Float16)(c0.y*rfv);
  ph[2] = (_Float16)(c0.z*rfv); ph[3] = (_Float16)(c0.w*rfv);
  ph[4] = (_Float16)(c1.x*rfv); ph[5] = (_Float16)(c1.y*rfv);
  ph[6] = (_Float16)(c1.z*rfv); ph[7] = (_Float16)(c1.w*rfv);
  *(half8v*)(pch + off) = ph;
}

// vertical 25-tap blur over fp16 tmp + sharpen(center pc) + sigmoid -> fp32 out.
// tile 64w x 128h, block 256 (16 wq x 16 rg). grid (8, 4, 48)
__global__ __launch_bounds__(256) void k_vblur(
    const _Float16* __restrict__ tmph, const _Float16* __restrict__ pch,
    const float* __restrict__ pbuf, const float* __restrict__ gw,
    float* __restrict__ out) {
  __shared__ _Float16 sh[152*64];   // rows h0-12 .. h0+139
  int tid = threadIdx.x;
  int bc = blockIdx.z, b = bc/3;
  int w0 = blockIdx.x*64, h0 = blockIdx.y*128;
  const _Float16* tr = tmph + (size_t)bc*NHW;
  for (int idx = tid; idx < 152*8; idx += 256) {
    int r = idx >> 3, seg = idx & 7;
    int gh = h0 - 12 + r;
    uint4 v = make_uint4(0u,0u,0u,0u);
    if (gh >= 0 && gh < NH) v = *(const uint4*)(tr + (size_t)gh*NW + w0 + seg*8);
    *(uint4*)&sh[r*64 + seg*8] = v;
  }
  __syncthreads();
  float kw[25];
#pragma unroll
  for (int j = 0; j < 25; j++) kw[j] = gw[j];
  int wq = tid & 15, rg = tid >> 4;
  int rowbase = rg*8;
  float4v acc[8];
#pragma unroll
  for (int i = 0; i < 8; i++) acc[i] = (float4v)0.f;
#pragma unroll
  for (int r = 0; r < 32; r++) {
    half4v hv = *(const half4v*)&sh[(rowbase + r)*64 + wq*4];
    float4v v = __builtin_convertvector(hv, float4v);
#pragma unroll
    for (int i = 0; i < 8; i++) {
      int j = r - i;
      if (j >= 0 && j < 25) acc[i] += kw[j]*v;
    }
  }
  float sharp = pbuf[b*32 + 15];
#pragma unroll
  for (int i = 0; i < 8; i++) {
    int h = h0 + rowbase + i;
    size_t off = (size_t)bc*NHW + (size_t)h*NW + w0 + wq*4;
    half4v pcv = *(const half4v*)(pch + off);
    float4v pc = __builtin_convertvector(pcv, float4v);
    float4v res = (pc - acc[i])*sharp + pc;
    float4v o;
    o.x = fast_rcp(1.f + fast_exp2(-res.x*LOG2E_F));
    o.y = fast_rcp(1.f + fast_exp2(-res.y*LOG2E_F));
    o.z = fast_rcp(1.f + fast_exp2(-res.z*LOG2E_F));
    o.w = fast_rcp(1.f + fast_exp2(-res.w*LOG2E_F));
    *(float4v*)(out + off) = o;
  }
}

extern "C" void kernel_launch(void* const* d_in, const int* in_sizes, int n_in,
                              void* d_out, int out_size, void* d_ws, size_t ws_size,
                              hipStream_t stream) {
  const float* x = (const float*)d_in[0];
  const float* params = (const float*)d_in[1];
  float* out = (float*)d_out;
  float* ws = (float*)d_ws;

  float* dark = ws + DARK_OFF;
  _Float16* tmph = (_Float16*)(ws + TMPH_OFF);
  _Float16* pch  = (_Float16*)(ws + PCH_OFF);
  unsigned* hist  = (unsigned*)(ws + HIST_OFF);
  unsigned* state = (unsigned*)(ws + STATE_OFF);
  unsigned* abits = (unsigned*)(ws + ABITS_OFF);
  float* pbuf = ws + PBUF_OFF;
  float* gw   = ws + GW_OFF;

  k_params<<<1, 256, 0, stream>>>(params, pbuf, gw, hist, abits);
  k_dark<<<dim3(NHW/2048, NB), 256, 0, stream>>>(x, dark, hist);
  k_scan<<<NB, 64, 0, stream>>>(hist, state, 0);
  k_hist<<<dim3(NHW/4096, NB), 256, 0, stream>>>((const unsigned*)dark, hist, state, 1);
  k_scan<<<NB, 64, 0, stream>>>(hist, state, 1);
  k_amax<<<dim3(NHW/2048, NB), 256, 0, stream>>>(x, dark, state, abits);
  k_hblur<<<dim3(NH/4, NB*NC), 256, 0, stream>>>(x, dark, pbuf, abits, gw, tmph, pch);
  k_vblur<<<dim3(NW/64, NH/128, NB*NC), 256, 0, stream>>>(tmph, pch, pbuf, gw, out);
}

// Round 5
// 151.523 us; speedup vs baseline: 1.9429x; 1.1808x over previous
//
#include <hip/hip_runtime.h>
#include <math.h>

#define NB 16
#define NC 3
#define NH 512
#define NW 512
#define NHW (NH*NW)
#define KSEL 26214u
#define PI_F 3.14159265358979f
#define LOG2E_F 1.44269504f

typedef _Float16 half4v __attribute__((ext_vector_type(4)));
typedef _Float16 half8v __attribute__((ext_vector_type(8)));
typedef float    float4v __attribute__((ext_vector_type(4)));

// ---- ws layout (float units) ----
#define TMPH_OFF   0                              // NB*NC*NHW fp16 (blurred-H)
#define PCH_OFF    (NB*NC*NHW/2)                  // NB*NC*NHW fp16 (post-contrast)
#define HIST_OFF   (PCH_OFF + NB*NC*NHW/2)        // NB*256 u32
#define BMAX_OFF   (HIST_OFF + NB*256)            // NB*3*256 u32 (per-bin channel max)
#define AVAL_OFF   (BMAX_OFF + NB*768)            // NB*3 f32
#define PBUF_OFF   (AVAL_OFF + NB*3)
#define GW_OFF     (PBUF_OFF + NB*32)
// total ~12.7M floats ~= 51 MB of ws

__device__ __forceinline__ float fast_rcp(float x)  { return __builtin_amdgcn_rcpf(x); }
__device__ __forceinline__ float fast_exp2(float x) { return __builtin_amdgcn_exp2f(x); }
__device__ __forceinline__ float fast_log2(float x) { return __builtin_amdgcn_logf(x); }

// pointwise chain through tone (pre contrast-scale): defog -> wb -> gamma -> tone
__device__ __forceinline__ float chain_tt(float xv, float dv, float omega, float Aval,
                                          float wbp, float g, const float* tone) {
  float t = fminf(fmaxf(1.f - omega*dv, 0.1f), 1.f);
  float J = (xv - Aval)*fast_rcp(t) + Aval;
  J = fminf(fmaxf(J, 0.f), 1.f);
  float v = J * wbp;
  float u = fast_exp2(g * fast_log2(fmaxf(v, 1e-4f)));   // pow(v,g), native
  float tt = 0.f;
#pragma unroll
  for (int i = 0; i < 8; i++)
    tt = fmaf(fminf(fmaxf(u - 0.125f*(float)i, 0.f), 0.125f), tone[i], tt);
  return tt;
}

// K1: parse params (one batch per block), gaussian weights, zero hist/binmax
__global__ void k_params(const float* __restrict__ p, float* __restrict__ pbuf,
                         float* __restrict__ gw, unsigned* __restrict__ hist,
                         unsigned* __restrict__ binmax) {
  int b = blockIdx.x, tid = threadIdx.x;
  if (tid == 0) {
    const float* pp = p + b*15;
    float* ob = pbuf + b*32;
    float omega = (tanhf(pp[0])+1.f)*0.5f*0.9f + 0.1f;
    float wb0 = 1.0f;  // mask=0 -> exp(0)=1
    float wb1 = expf((tanhf(pp[2])+1.f)*0.5f - 0.5f);
    float wb2 = expf((tanhf(pp[3])+1.f)*0.5f - 0.5f);
    float denom = 0.27f*wb0 + 0.67f*wb1 + 0.06f*wb2 + 1e-5f;
    float lg = logf(3.0f);
    float g = expf((tanhf(pp[4])+1.f)*0.5f*(2.f*lg) - lg);
    float ts = 0.f, tone[8];
    for (int i = 0; i < 8; i++) { tone[i] = (tanhf(pp[5+i])+1.f)*0.5f*1.5f + 0.5f; ts += tone[i]; }
    ts += 1e-30f;
    ob[0] = omega; ob[1] = wb0/denom; ob[2] = wb1/denom; ob[3] = wb2/denom; ob[4] = g;
    for (int i = 0; i < 8; i++) ob[5+i] = tone[i];
    ob[13] = 8.0f/ts;            // tonescale
    ob[14] = tanhf(pp[13]);      // contrast c
    ob[15] = (tanhf(pp[14])+1.f)*0.5f*5.0f;  // sharpen
  }
  if (b == 0 && tid == 64) {
    float wv[25], wsum = 0.f;
    for (int i = 0; i < 25; i++) { float d = (float)(i-12)/5.0f; wv[i] = expf(-0.5f*d*d); wsum += wv[i]; }
    for (int i = 0; i < 25; i++) gw[i] = wv[i]/wsum;
  }
  hist[b*256 + tid] = 0u;
  for (int i = tid; i < 768; i += 256) binmax[b*768 + i] = 0u;
}

// K2: dark (in-register) -> top-byte histogram + per-bin per-channel max of x.
// grid (64, NB) x 256; each block 4096 px.
__global__ __launch_bounds__(256) void k_stats(const float* __restrict__ x,
                                               unsigned* __restrict__ hist,
                                               unsigned* __restrict__ binmax) {
  __shared__ unsigned lh[8*256];     // hist replicas
  __shared__ unsigned lbm[4][768];   // binmax replicas [rep][c*256+bin]
  int tid = threadIdx.x, b = blockIdx.y;
  for (int i = tid; i < 8*256; i += 256) lh[i] = 0u;
  for (int i = tid; i < 4*768; i += 256) ((unsigned*)lbm)[i] = 0u;
  __syncthreads();
  const float4* x0 = (const float4*)(x + (size_t)b*NC*NHW);
  const float4* x1 = x0 + NHW/4;
  const float4* x2 = x1 + NHW/4;
  unsigned* lhm = lh + (tid & 7)*256;
  unsigned* bmr = lbm[tid & 3];
  int base = blockIdx.x*1024 + tid;
#pragma unroll
  for (int it = 0; it < 4; it++) {
    int i = base + it*256;
    float4 a = x0[i], g = x1[i], r = x2[i];
    float dv[4] = { fminf(fminf(a.x,g.x),r.x), fminf(fminf(a.y,g.y),r.y),
                    fminf(fminf(a.z,g.z),r.z), fminf(fminf(a.w,g.w),r.w) };
    float av[4] = {a.x,a.y,a.z,a.w}, gv[4] = {g.x,g.y,g.z,g.w}, rv[4] = {r.x,r.y,r.z,r.w};
#pragma unroll
    for (int q = 0; q < 4; q++) {
      unsigned bin = __float_as_uint(dv[q]) >> 24;
      atomicAdd(&lhm[bin], 1u);
      atomicMax(&bmr[bin],       __float_as_uint(av[q]));
      atomicMax(&bmr[256 + bin], __float_as_uint(gv[q]));
      atomicMax(&bmr[512 + bin], __float_as_uint(rv[q]));
    }
  }
  __syncthreads();
  {
    unsigned s = 0;
    for (int r2 = 0; r2 < 8; r2++) s += lh[r2*256 + tid];
    if (s) atomicAdd(&hist[b*256 + tid], s);
  }
  for (int idx = tid; idx < 768; idx += 256) {
    unsigned m = lbm[0][idx];
    m = max(m, lbm[1][idx]); m = max(m, lbm[2][idx]); m = max(m, lbm[3][idx]);
    if (m) atomicMax(&binmax[b*768 + idx], m);
  }
}

// K3: find bin b* holding the k-th largest dark value; A[b,c] = suffix-max of
// binmax over bins >= b*. grid NB x 64 (one wave).
__global__ void k_scan(const unsigned* __restrict__ hist,
                       const unsigned* __restrict__ binmax,
                       float* __restrict__ avals) {
  int b = blockIdx.x, lane = threadIdx.x;
  unsigned cnt[4], s = 0;
#pragma unroll
  for (int j = 0; j < 4; j++) { cnt[j] = hist[b*256 + (255 - (lane*4+j))]; s += cnt[j]; }
  unsigned inc = s;
  for (int off = 1; off < 64; off <<= 1) {
    unsigned n = __shfl_up(inc, off);
    if (lane >= off) inc += n;
  }
  unsigned excl = inc - s;
  bool found = (excl < KSEL && KSEL <= inc);
  int localBin = 0;
  if (found) {
    unsigned run = excl; int binj = 0;
#pragma unroll
    for (int j = 0; j < 4; j++) {
      unsigned nb = run + cnt[j];
      if (KSEL > run && KSEL <= nb) binj = j;
      run = nb;
    }
    localBin = 255 - (lane*4 + binj);
  }
  unsigned long long mask = __ballot(found ? 1 : 0);
  int src = (int)__ffsll((long long)mask) - 1;
  int bstar = __shfl(localBin, src);
#pragma unroll
  for (int c = 0; c < 3; c++) {
    float m = 0.f;
#pragma unroll
    for (int j = 0; j < 4; j++) {
      int bin = 255 - (lane*4 + j);
      if (bin >= bstar) m = fmaxf(m, __uint_as_float(binmax[b*768 + c*256 + bin]));
    }
    for (int off = 1; off < 64; off <<= 1) m = fmaxf(m, __shfl_xor(m, off));
    if (lane == 0) avals[b*3 + c] = m;
  }
}

// K4: 3-channel horizontal 25-tap blur; dark recomputed in-register, chain fused,
// per-row contrast factor in-block. Writes blurred row + post-contrast center (fp16).
// block = 4 rows x 64 lanes; grid (128, NB).
__global__ __launch_bounds__(256) void k_hblur(
    const float* __restrict__ x, const float* __restrict__ pbuf,
    const float* __restrict__ avals, const float* __restrict__ gw,
    _Float16* __restrict__ tmph, _Float16* __restrict__ pch) {
  __shared__ __align__(16) float pcp[3][4][544];   // 16 pad | 512 | 16 pad
  __shared__ float rfs[4][3];
  int tid = threadIdx.x;
  int row = tid >> 6, lane = tid & 63;
  int b = blockIdx.y;
  int h = blockIdx.x*4 + row;
  const float* pb = pbuf + b*32;
  float omega = pb[0], g = pb[4], ts = pb[13], cc = pb[14];
  float wbp[3] = {pb[1], pb[2], pb[3]};
  float tone[8];
#pragma unroll
  for (int i = 0; i < 8; i++) tone[i] = pb[5+i];
  float Av[3] = {avals[b*3], avals[b*3+1], avals[b*3+2]};
  if (lane < 16) {
#pragma unroll
    for (int c = 0; c < 3; c++) { pcp[c][row][lane] = 0.f; pcp[c][row][528 + lane] = 0.f; }
  }
  const float4* xr0 = (const float4*)(x + ((size_t)b*3 + 0)*NHW + (size_t)h*NW);
  const float4* xr1 = (const float4*)(x + ((size_t)b*3 + 1)*NHW + (size_t)h*NW);
  const float4* xr2 = (const float4*)(x + ((size_t)b*3 + 2)*NHW + (size_t)h*NW);
#pragma unroll
  for (int m = 0; m < 2; m++) {
    int i4 = lane + m*64;
    float4 v0 = xr0[i4], v1 = xr1[i4], v2 = xr2[i4];
    float4 d;
    d.x = fminf(fminf(v0.x,v1.x),v2.x); d.y = fminf(fminf(v0.y,v1.y),v2.y);
    d.z = fminf(fminf(v0.z,v1.z),v2.z); d.w = fminf(fminf(v0.w,v1.w),v2.w);
    float4 p0, p1, p2;
    p0.x = chain_tt(v0.x, d.x, omega, Av[0], wbp[0], g, tone);
    p0.y = chain_tt(v0.y, d.y, omega, Av[0], wbp[0], g, tone);
    p0.z = chain_tt(v0.z, d.z, omega, Av[0], wbp[0], g, tone);
    p0.w = chain_tt(v0.w, d.w, omega, Av[0], wbp[0], g, tone);
    p1.x = chain_tt(v1.x, d.x, omega, Av[1], wbp[1], g, tone);
    p1.y = chain_tt(v1.y, d.y, omega, Av[1], wbp[1], g, tone);
    p1.z = chain_tt(v1.z, d.z, omega, Av[1], wbp[1], g, tone);
    p1.w = chain_tt(v1.w, d.w, omega, Av[1], wbp[1], g, tone);
    p2.x = chain_tt(v2.x, d.x, omega, Av[2], wbp[2], g, tone);
    p2.y = chain_tt(v2.y, d.y, omega, Av[2], wbp[2], g, tone);
    p2.z = chain_tt(v2.z, d.z, omega, Av[2], wbp[2], g, tone);
    p2.w = chain_tt(v2.w, d.w, omega, Av[2], wbp[2], g, tone);
    *(float4*)&pcp[0][row][16 + i4*4] = p0;
    *(float4*)&pcp[1][row][16 + i4*4] = p1;
    *(float4*)&pcp[2][row][16 + i4*4] = p2;
  }
  __syncthreads();
  if (lane < 3) {
    // contrast lum uses W-columns 0..2 of channel `lane`
    int c = lane;
    float p0 = pcp[c][row][16]*ts, p1 = pcp[c][row][17]*ts, p2 = pcp[c][row][18]*ts;
    float lum = fminf(fmaxf(0.27f*p0 + 0.67f*p1 + 0.06f*p2, 0.f), 1.f);
    float cl = 0.5f - 0.5f*__cosf(PI_F*lum);
    rfs[row][c] = ts*((1.f - cc) + cc*cl*fast_rcp(lum + 1e-6f));
  }
  __syncthreads();
  float kw[25];
#pragma unroll
  for (int j = 0; j < 25; j++) kw[j] = gw[j];
#pragma unroll
  for (int c = 0; c < 3; c++) {
    float rfv = rfs[row][c];
    float acc[8] = {0,0,0,0,0,0,0,0};
    const float* rowp = &pcp[c][row][lane*8 + 4];
#pragma unroll
    for (int r = 0; r < 8; r++) {
      float4 v = *(const float4*)(rowp + r*4);
      float vs[4] = {v.x, v.y, v.z, v.w};
#pragma unroll
      for (int q = 0; q < 4; q++) {
        int idx = r*4 + q;
#pragma unroll
        for (int i = 0; i < 8; i++) {
          int j = idx - i;
          if (j >= 0 && j < 25) acc[i] = fmaf(kw[j], vs[q], acc[i]);
        }
      }
    }
    size_t off = ((size_t)b*3 + c)*NHW + (size_t)h*NW + lane*8;
    half8v th;
#pragma unroll
    for (int i = 0; i < 8; i++) th[i] = (_Float16)(acc[i]*rfv);
    *(half8v*)(tmph + off) = th;
    float4 c0 = *(float4*)&pcp[c][row][16 + lane*8];
    float4 c1 = *(float4*)&pcp[c][row][20 + lane*8];
    half8v ph;
    ph[0] = (_Float16)(c0.x*rfv); ph[1] = (_Float16)(c0.y*rfv);
    ph[2] = (_Float16)(c0.z*rfv); ph[3] = (_Float16)(c0.w*rfv);
    ph[4] = (_Float16)(c1.x*rfv); ph[5] = (_Float16)(c1.y*rfv);
    ph[6] = (_Float16)(c1.z*rfv); ph[7] = (_Float16)(c1.w*rfv);
    *(half8v*)(pch + off) = ph;
  }
}

// K5: vertical 25-tap blur over fp16 tmp + sharpen(center pc) + sigmoid -> fp32 out.
// tile 64w x 128h, block 256 (16 wq x 16 rg). grid (8, 4, 48)
__global__ __launch_bounds__(256) void k_vblur(
    const _Float16* __restrict__ tmph, const _Float16* __restrict__ pch,
    const float* __restrict__ pbuf, const float* __restrict__ gw,
    float* __restrict__ out) {
  __shared__ _Float16 sh[152*64];   // rows h0-12 .. h0+139
  int tid = threadIdx.x;
  int bc = blockIdx.z, b = bc/3;
  int w0 = blockIdx.x*64, h0 = blockIdx.y*128;
  const _Float16* tr = tmph + (size_t)bc*NHW;
  for (int idx = tid; idx < 152*8; idx += 256) {
    int r = idx >> 3, seg = idx & 7;
    int gh = h0 - 12 + r;
    uint4 v = make_uint4(0u,0u,0u,0u);
    if (gh >= 0 && gh < NH) v = *(const uint4*)(tr + (size_t)gh*NW + w0 + seg*8);
    *(uint4*)&sh[r*64 + seg*8] = v;
  }
  __syncthreads();
  float kw[25];
#pragma unroll
  for (int j = 0; j < 25; j++) kw[j] = gw[j];
  int wq = tid & 15, rg = tid >> 4;
  int rowbase = rg*8;
  float4v acc[8];
#pragma unroll
  for (int i = 0; i < 8; i++) acc[i] = (float4v)0.f;
#pragma unroll
  for (int r = 0; r < 32; r++) {
    half4v hv = *(const half4v*)&sh[(rowbase + r)*64 + wq*4];
    float4v v = __builtin_convertvector(hv, float4v);
#pragma unroll
    for (int i = 0; i < 8; i++) {
      int j = r - i;
      if (j >= 0 && j < 25) acc[i] += kw[j]*v;
    }
  }
  float sharp = pbuf[b*32 + 15];
#pragma unroll
  for (int i = 0; i < 8; i++) {
    int h = h0 + rowbase + i;
    size_t off = (size_t)bc*NHW + (size_t)h*NW + w0 + wq*4;
    half4v pcv = *(const half4v*)(pch + off);
    float4v pc = __builtin_convertvector(pcv, float4v);
    float4v res = (pc - acc[i])*sharp + pc;
    float4v o;
    o.x = fast_rcp(1.f + fast_exp2(-res.x*LOG2E_F));
    o.y = fast_rcp(1.f + fast_exp2(-res.y*LOG2E_F));
    o.z = fast_rcp(1.f + fast_exp2(-res.z*LOG2E_F));
    o.w = fast_rcp(1.f + fast_exp2(-res.w*LOG2E_F));
    *(float4v*)(out + off) = o;
  }
}

extern "C" void kernel_launch(void* const* d_in, const int* in_sizes, int n_in,
                              void* d_out, int out_size, void* d_ws, size_t ws_size,
                              hipStream_t stream) {
  const float* x = (const float*)d_in[0];
  const float* params = (const float*)d_in[1];
  float* out = (float*)d_out;
  float* ws = (float*)d_ws;

  _Float16* tmph = (_Float16*)(ws + TMPH_OFF);
  _Float16* pch  = (_Float16*)(ws + PCH_OFF);
  unsigned* hist   = (unsigned*)(ws + HIST_OFF);
  unsigned* binmax = (unsigned*)(ws + BMAX_OFF);
  float* avals = ws + AVAL_OFF;
  float* pbuf  = ws + PBUF_OFF;
  float* gw    = ws + GW_OFF;

  k_params<<<NB, 256, 0, stream>>>(params, pbuf, gw, hist, binmax);
  k_stats<<<dim3(64, NB), 256, 0, stream>>>(x, hist, binmax);
  k_scan<<<NB, 64, 0, stream>>>(hist, binmax, avals);
  k_hblur<<<dim3(NH/4, NB), 256, 0, stream>>>(x, pbuf, avals, gw, tmph, pch);
  k_vblur<<<dim3(NW/64, NH/128, NB*NC), 256, 0, stream>>>(tmph, pch, pbuf, gw, out);
}